// Round 1
// baseline (98.150 us; speedup 1.0000x reference)
//
#include <hip/hip_runtime.h>

#define N_PTS 65536
#define T_DIM 32
#define P_DIM 16

// ws layout (floats):
//   [0, 6144)        Rt: entry (t*16+p)*12 = {R row-major (9), t (3)}
//   [6144, 6144+2560) wpack: row k*20 = {w1[k][0..2], b1[k], w2[0..15][k]}
//   [6144+2560, +16)  b2
__global__ void prep_kernel(const float* __restrict__ d6,
                            const float* __restrict__ pt,
                            const float* __restrict__ w1,
                            const float* __restrict__ b1,
                            const float* __restrict__ w2,
                            const float* __restrict__ b2,
                            float* __restrict__ ws,
                            float* __restrict__ out_trans)
{
    int idx = blockIdx.x * blockDim.x + threadIdx.x;
    if (idx < T_DIM * P_DIM) {
        const float* a = d6 + idx * 6;
        float a1x=a[0], a1y=a[1], a1z=a[2], a2x=a[3], a2y=a[4], a2z=a[5];
        float n1 = sqrtf(a1x*a1x + a1y*a1y + a1z*a1z);
        float b1x=a1x/n1, b1y=a1y/n1, b1z=a1z/n1;
        float d = b1x*a2x + b1y*a2y + b1z*a2z;
        float px = a2x - d*b1x, py = a2y - d*b1y, pz = a2z - d*b1z;
        float n2 = sqrtf(px*px + py*py + pz*pz);
        float b2x=px/n2, b2y=py/n2, b2z=pz/n2;
        float b3x = b1y*b2z - b1z*b2y;
        float b3y = b1z*b2x - b1x*b2z;
        float b3z = b1x*b2y - b1y*b2x;
        float t0 = pt[idx*3+0], t1 = pt[idx*3+1], t2 = pt[idx*3+2];
        float* R = ws + idx*12;
        R[0]=b1x; R[1]=b1y; R[2]=b1z;
        R[3]=b2x; R[4]=b2y; R[5]=b2z;
        R[6]=b3x; R[7]=b3y; R[8]=b3z;
        R[9]=t0;  R[10]=t1; R[11]=t2;
        float* o = out_trans + idx*16;
        o[0]=b1x; o[1]=b1y; o[2]=b1z;  o[3]=t0;
        o[4]=b2x; o[5]=b2y; o[6]=b2z;  o[7]=t1;
        o[8]=b3x; o[9]=b3y; o[10]=b3z; o[11]=t2;
        o[12]=0.f; o[13]=0.f; o[14]=0.f; o[15]=1.f;
    }
    int k = idx - 512;
    if (k >= 0 && k < 128) {
        float* wp = ws + 6144 + k*20;
        wp[0]=w1[k*3+0]; wp[1]=w1[k*3+1]; wp[2]=w1[k*3+2]; wp[3]=b1[k];
        #pragma unroll
        for (int p=0;p<16;p++) wp[4+p] = w2[p*128+k];
    }
    if (idx < 16) ws[6144+2560+idx] = b2[idx];
}

__global__ __launch_bounds__(256) void main_kernel(
    const float* __restrict__ pc,
    const float* __restrict__ gumbel,
    const float* __restrict__ ws,
    float* __restrict__ out_pc,
    float* __restrict__ out_idx)
{
    __shared__ __align__(16) float s_Rt[6144];
    int tid = threadIdx.x;
    {
        const float4* src = (const float4*)ws;
        float4* dst = (float4*)s_Rt;
        for (int i = tid; i < 1536; i += 256) dst[i] = src[i];
    }
    __syncthreads();

    int n = blockIdx.x * 256 + tid;
    float x0 = pc[n*3+0], x1 = pc[n*3+1], x2 = pc[n*3+2];

    const float* wpack = ws + 6144;
    float seg[16];
    #pragma unroll
    for (int p=0;p<16;p++) seg[p] = wpack[2560+p];

    // MLP: seg[p] = b2[p] + sum_k w2[p][k] * relu(w1[k]·x + b1[k])
    // wpack rows are wave-uniform -> scalar (SMEM) loads expected.
    #pragma unroll 4
    for (int k=0;k<128;k++) {
        const float* wp = wpack + k*20;
        float h = fmaf(wp[0], x0, wp[3]);
        h = fmaf(wp[1], x1, h);
        h = fmaf(wp[2], x2, h);
        h = fmaxf(h, 0.0f);
        #pragma unroll
        for (int p=0;p<16;p++) seg[p] = fmaf(wp[4+p], h, seg[p]);
    }

    // argmax(seg) — first-index-wins, matches np.argmax
    float best = seg[0]; int pseg = 0;
    #pragma unroll
    for (int p=1;p<16;p++) { if (seg[p] > best) { best = seg[p]; pseg = p; } }
    out_idx[n] = (float)pseg;

    // p* = argmax(seg + gumbel)  (TAU=1, softmax monotone -> same argmax;
    // weight = hard + y - y == one_hot(p*) to ~1e-7)
    float g[16];
    {
        const float4* g4 = (const float4*)(gumbel + n*16);
        #pragma unroll
        for (int j=0;j<4;j++) { float4 v = g4[j]; g[4*j]=v.x; g[4*j+1]=v.y; g[4*j+2]=v.z; g[4*j+3]=v.w; }
    }
    float bestg = seg[0] + g[0]; int pstar = 0;
    #pragma unroll
    for (int p=1;p<16;p++) { float v = seg[p] + g[p]; if (v > bestg) { bestg = v; pstar = p; } }

    // pc_out[t,n,:] = R[t,p*] @ x + t[t,p*]
    const float* Rb = s_Rt + pstar*12;
    for (int t=0;t<T_DIM;t++) {
        const float* R = Rb + t*192;
        float4 r0 = *(const float4*)(R);      // R00 R01 R02 R10
        float4 r1 = *(const float4*)(R+4);    // R11 R12 R20 R21
        float4 r2 = *(const float4*)(R+8);    // R22 t0  t1  t2
        float y0 = fmaf(r0.x, x0, r2.y); y0 = fmaf(r0.y, x1, y0); y0 = fmaf(r0.z, x2, y0);
        float y1 = fmaf(r0.w, x0, r2.z); y1 = fmaf(r1.x, x1, y1); y1 = fmaf(r1.y, x2, y1);
        float y2 = fmaf(r1.z, x0, r2.w); y2 = fmaf(r1.w, x1, y2); y2 = fmaf(r2.x, x2, y2);
        float* o = out_pc + (t * N_PTS + n) * 3;
        o[0]=y0; o[1]=y1; o[2]=y2;
    }
}

extern "C" void kernel_launch(void* const* d_in, const int* in_sizes, int n_in,
                              void* d_out, int out_size, void* d_ws, size_t ws_size,
                              hipStream_t stream)
{
    const float* pc  = (const float*)d_in[0];
    const float* w1  = (const float*)d_in[1];
    const float* b1  = (const float*)d_in[2];
    const float* w2  = (const float*)d_in[3];
    const float* b2  = (const float*)d_in[4];
    const float* d6  = (const float*)d_in[5];
    const float* pt  = (const float*)d_in[6];
    const float* gum = (const float*)d_in[7];
    float* out = (float*)d_out;
    float* ws  = (float*)d_ws;

    float* out_pc    = out;                        // T*N*3 = 6291456
    float* out_idx   = out + 6291456;              // N     = 65536
    float* out_trans = out + 6291456 + 65536;      // T*P*16 = 8192

    prep_kernel<<<3, 256, 0, stream>>>(d6, pt, w1, b1, w2, b2, ws, out_trans);
    main_kernel<<<256, 256, 0, stream>>>(pc, gum, ws, out_pc, out_idx);
}

// Round 2
// 87.662 us; speedup vs baseline: 1.1196x; 1.1196x over previous
//
#include <hip/hip_runtime.h>

#define N_PTS 65536
#define T_DIM 32
#define P_DIM 16

// ws float layout:
//   [0, 7168)      R rows: (t*16+p)*14 = {R row-major (9), t (3), pad(2)}
//   [7168, 9728)   wpack: k*20 = {w1[k][0..2], b1[k], w2[0..15][k]}
//   [9728, 9744)   b2
__global__ void prep_kernel(const float* __restrict__ d6,
                            const float* __restrict__ pt,
                            const float* __restrict__ w1,
                            const float* __restrict__ b1,
                            const float* __restrict__ w2,
                            const float* __restrict__ b2,
                            float* __restrict__ ws,
                            float* __restrict__ out_trans)
{
    int idx = blockIdx.x * blockDim.x + threadIdx.x;
    if (idx < T_DIM * P_DIM) {
        const float* a = d6 + idx * 6;
        float a1x=a[0], a1y=a[1], a1z=a[2], a2x=a[3], a2y=a[4], a2z=a[5];
        float n1 = sqrtf(a1x*a1x + a1y*a1y + a1z*a1z);
        float b1x=a1x/n1, b1y=a1y/n1, b1z=a1z/n1;
        float d = b1x*a2x + b1y*a2y + b1z*a2z;
        float px = a2x - d*b1x, py = a2y - d*b1y, pz = a2z - d*b1z;
        float n2 = sqrtf(px*px + py*py + pz*pz);
        float b2x=px/n2, b2y=py/n2, b2z=pz/n2;
        float b3x = b1y*b2z - b1z*b2y;
        float b3y = b1z*b2x - b1x*b2z;
        float b3z = b1x*b2y - b1y*b2x;
        float t0 = pt[idx*3+0], t1 = pt[idx*3+1], t2 = pt[idx*3+2];
        float* R = ws + idx*14;
        R[0]=b1x; R[1]=b1y; R[2]=b1z;
        R[3]=b2x; R[4]=b2y; R[5]=b2z;
        R[6]=b3x; R[7]=b3y; R[8]=b3z;
        R[9]=t0;  R[10]=t1; R[11]=t2;
        R[12]=0.f; R[13]=0.f;
        float* o = out_trans + idx*16;
        o[0]=b1x; o[1]=b1y; o[2]=b1z;  o[3]=t0;
        o[4]=b2x; o[5]=b2y; o[6]=b2z;  o[7]=t1;
        o[8]=b3x; o[9]=b3y; o[10]=b3z; o[11]=t2;
        o[12]=0.f; o[13]=0.f; o[14]=0.f; o[15]=1.f;
    }
    int k = idx - 512;
    if (k >= 0 && k < 128) {
        float* wp = ws + 7168 + k*20;
        wp[0]=w1[k*3+0]; wp[1]=w1[k*3+1]; wp[2]=w1[k*3+2]; wp[3]=b1[k];
        #pragma unroll
        for (int p=0;p<16;p++) wp[4+p] = w2[p*128+k];
    }
    if (idx < 16) ws[9728+idx] = b2[idx];
}

// Block = 64 points, 4 waves. Phase 1: waves split k (32 each), weights via
// wave-uniform s_load. Phase 2: all waves do transforms, R staged in LDS with
// row stride 14 (conflict-free pstar gather). LDS 28.9 KB -> 5 blocks/CU.
__global__ __launch_bounds__(256) void fused_kernel(
    const float* __restrict__ pc,
    const float* __restrict__ gumbel,
    const float* __restrict__ ws,
    float* __restrict__ out_pc,
    float* __restrict__ out_idx)
{
    __shared__ __align__(16) float smem[7168 + 64];  // R stage (overlays partials) + pstar
    const int tid  = threadIdx.x;
    const int lane = tid & 63;
    const int wv   = __builtin_amdgcn_readfirstlane(tid >> 6);  // force SGPR
    const int n    = blockIdx.x * 64 + lane;

    const float x0 = pc[n*3+0], x1 = pc[n*3+1], x2 = pc[n*3+2];

    // ---- Phase 1: partial MLP over k in [wv*32, wv*32+32) ----
    const float* wpk = ws + 7168 + wv*32*20;   // scalar base -> s_load rows
    float seg[16];
    if (wv == 0) {
        const float* b2p = ws + 9728;
        #pragma unroll
        for (int p=0;p<16;p++) seg[p] = b2p[p];
    } else {
        #pragma unroll
        for (int p=0;p<16;p++) seg[p] = 0.f;
    }
    #pragma unroll 8
    for (int k=0;k<32;k++) {
        const float* wp = wpk + k*20;
        float h = fmaf(wp[0], x0, wp[3]);
        h = fmaf(wp[1], x1, h);
        h = fmaf(wp[2], x2, h);
        h = fmaxf(h, 0.0f);
        #pragma unroll
        for (int p=0;p<16;p++) seg[p] = fmaf(wp[4+p], h, seg[p]);
    }
    // partials: [wv][p][lane] — lane-major, 2 lanes/bank = free
    #pragma unroll
    for (int p=0;p<16;p++) smem[wv*1024 + p*64 + lane] = seg[p];
    __syncthreads();

    // ---- Reduce + argmax (wave 0 only) ----
    if (wv == 0) {
        float s[16];
        #pragma unroll
        for (int p=0;p<16;p++) {
            float v = smem[p*64 + lane] + smem[1024 + p*64 + lane];
            v += smem[2048 + p*64 + lane] + smem[3072 + p*64 + lane];
            s[p] = v;
        }
        float best = s[0]; int pseg = 0;
        #pragma unroll
        for (int p=1;p<16;p++) { if (s[p] > best) { best = s[p]; pseg = p; } }
        out_idx[n] = (float)pseg;

        float g[16];
        const float4* g4 = (const float4*)(gumbel + (size_t)n*16);
        #pragma unroll
        for (int j=0;j<4;j++) { float4 v = g4[j]; g[4*j]=v.x; g[4*j+1]=v.y; g[4*j+2]=v.z; g[4*j+3]=v.w; }
        float bg = s[0] + g[0]; int pstar = 0;
        #pragma unroll
        for (int p=1;p<16;p++) { float v = s[p] + g[p]; if (v > bg) { bg = v; pstar = p; } }
        smem[7168 + lane] = (float)pstar;
    }
    __syncthreads();

    // ---- Stage R table into LDS (overwrites partial region) ----
    {
        const float2* src = (const float2*)ws;   // 7168 floats = 3584 float2
        float2* dst = (float2*)smem;
        #pragma unroll
        for (int i=0;i<14;i++) dst[tid + i*256] = src[tid + i*256];
    }
    __syncthreads();

    // ---- Phase 2: 8 transforms per thread, t = wv*8 + i ----
    const int p = (int)smem[7168 + lane];
    const float* Rb = smem + p*14;
    #pragma unroll
    for (int i=0;i<8;i++) {
        const int t = wv*8 + i;
        const float* R = Rb + t*224;  // (t*16+p)*14
        float2 r01 = *(const float2*)(R);
        float2 r23 = *(const float2*)(R+2);
        float2 r45 = *(const float2*)(R+4);
        float2 r67 = *(const float2*)(R+6);
        float2 r8t = *(const float2*)(R+8);
        float2 t12 = *(const float2*)(R+10);
        float y0 = fmaf(r01.x, x0, r8t.y); y0 = fmaf(r01.y, x1, y0); y0 = fmaf(r23.x, x2, y0);
        float y1 = fmaf(r23.y, x0, t12.x); y1 = fmaf(r45.x, x1, y1); y1 = fmaf(r45.y, x2, y1);
        float y2 = fmaf(r67.x, x0, t12.y); y2 = fmaf(r67.y, x1, y2); y2 = fmaf(r8t.x, x2, y2);
        float* o = out_pc + ((size_t)t * N_PTS + n) * 3;
        o[0]=y0; o[1]=y1; o[2]=y2;
    }
}

extern "C" void kernel_launch(void* const* d_in, const int* in_sizes, int n_in,
                              void* d_out, int out_size, void* d_ws, size_t ws_size,
                              hipStream_t stream)
{
    const float* pc  = (const float*)d_in[0];
    const float* w1  = (const float*)d_in[1];
    const float* b1  = (const float*)d_in[2];
    const float* w2  = (const float*)d_in[3];
    const float* b2  = (const float*)d_in[4];
    const float* d6  = (const float*)d_in[5];
    const float* pt  = (const float*)d_in[6];
    const float* gum = (const float*)d_in[7];
    float* out = (float*)d_out;
    float* ws  = (float*)d_ws;

    float* out_pc    = out;                        // T*N*3 = 6291456
    float* out_idx   = out + 6291456;              // N     = 65536
    float* out_trans = out + 6291456 + 65536;      // T*P*16 = 8192

    prep_kernel<<<3, 256, 0, stream>>>(d6, pt, w1, b1, w2, b2, ws, out_trans);
    fused_kernel<<<1024, 256, 0, stream>>>(pc, gum, ws, out_pc, out_idx);
}